// Round 13
// baseline (87.115 us; speedup 1.0000x reference)
//
#include <hip/hip_runtime.h>

#define NN 256
#define XPW 8              // pairs (x values) per wave
#define NXS (NN/(4*XPW))   // 8 xsel groups

typedef float vf4 __attribute__((ext_vector_type(4)));

// hard-coded CG constants (l<=2), float32
#define C13  0.5773502691896258f
#define C15  0.4472135954999579f
#define CC12 0.7071067811865476f
#define S35  0.7745966692414834f
#define S310 0.5477225575051661f
#define C110 0.3162277660168379f
#define S25  0.6324555320336759f
#define S23  0.8164965809277260f
#define C16  0.4082482904638630f
#define S27  0.5345224838248488f
#define S37  0.6546536707079771f
#define C114 0.2672612419124244f

#define CGREL(mx, sv, r0, r1, r2) \
    r0[0] = mx[0]*sv[0]; \
    r0[1] = C13*(mx[1]*sv[3] - mx[2]*sv[2] + mx[3]*sv[1]); \
    r0[2] = C15*(mx[4]*sv[8] - mx[5]*sv[7] + mx[6]*sv[6] - mx[7]*sv[5] + mx[8]*sv[4]); \
    r1[0][0] = mx[0]*sv[1]; r1[1][0] = mx[0]*sv[2]; r1[2][0] = mx[0]*sv[3]; \
    r1[0][1] = mx[1]*sv[0]; r1[1][1] = mx[2]*sv[0]; r1[2][1] = mx[3]*sv[0]; \
    r1[0][2] = CC12*(mx[2]*sv[1] - mx[1]*sv[2]); \
    r1[1][2] = CC12*(mx[3]*sv[1] - mx[1]*sv[3]); \
    r1[2][2] = CC12*(mx[3]*sv[2] - mx[2]*sv[3]); \
    r1[0][3] = S35*mx[3]*sv[4] - S310*mx[2]*sv[5] + C110*mx[1]*sv[6]; \
    r1[1][3] = S310*(mx[3]*sv[5] + mx[1]*sv[7]) - S25*mx[2]*sv[6]; \
    r1[2][3] = S35*mx[1]*sv[8] - S310*mx[2]*sv[7] + C110*mx[3]*sv[6]; \
    r1[0][4] = C110*mx[6]*sv[1] - S310*mx[5]*sv[2] + S35*mx[4]*sv[3]; \
    r1[1][4] = S310*(mx[7]*sv[1] + mx[5]*sv[3]) - S25*mx[6]*sv[2]; \
    r1[2][4] = S35*mx[8]*sv[1] - S310*mx[7]*sv[2] + C110*mx[6]*sv[3]; \
    r1[0][5] = C15*(mx[7]*sv[4] - mx[4]*sv[7]) + S310*(mx[5]*sv[6] - mx[6]*sv[5]); \
    r1[1][5] = S25*(mx[8]*sv[4] - mx[4]*sv[8]) + C110*(mx[5]*sv[7] - mx[7]*sv[5]); \
    r1[2][5] = C15*(mx[8]*sv[5] - mx[5]*sv[8]) + S310*(mx[6]*sv[7] - mx[7]*sv[6]); \
    r2[0][0]=mx[0]*sv[4]; r2[1][0]=mx[0]*sv[5]; r2[2][0]=mx[0]*sv[6]; r2[3][0]=mx[0]*sv[7]; r2[4][0]=mx[0]*sv[8]; \
    r2[0][1] = mx[1]*sv[1]; \
    r2[1][1] = CC12*(mx[2]*sv[1] + mx[1]*sv[2]); \
    r2[2][1] = C16*(mx[3]*sv[1] + mx[1]*sv[3]) + S23*mx[2]*sv[2]; \
    r2[3][1] = CC12*(mx[3]*sv[2] + mx[2]*sv[3]); \
    r2[4][1] = mx[3]*sv[3]; \
    r2[0][2] = S23*mx[2]*sv[4] - C13*mx[1]*sv[5]; \
    r2[1][2] = C13*mx[3]*sv[4] + C16*mx[2]*sv[5] - CC12*mx[1]*sv[6]; \
    r2[2][2] = CC12*(mx[3]*sv[5] - mx[1]*sv[7]); \
    r2[3][2] = CC12*mx[3]*sv[6] - C16*mx[2]*sv[7] - C13*mx[1]*sv[8]; \
    r2[4][2] = C13*mx[3]*sv[7] - S23*mx[2]*sv[8]; \
    r2[0][3]=mx[4]*sv[0]; r2[1][3]=mx[5]*sv[0]; r2[2][3]=mx[6]*sv[0]; r2[3][3]=mx[7]*sv[0]; r2[4][3]=mx[8]*sv[0]; \
    r2[0][4] = C13*mx[5]*sv[1] - S23*mx[4]*sv[2]; \
    r2[1][4] = CC12*mx[6]*sv[1] - C16*mx[5]*sv[2] - C13*mx[4]*sv[3]; \
    r2[2][4] = CC12*(mx[7]*sv[1] - mx[5]*sv[3]); \
    r2[3][4] = C13*mx[8]*sv[1] + C16*mx[7]*sv[2] - CC12*mx[6]*sv[3]; \
    r2[4][4] = S23*mx[8]*sv[2] - C13*mx[7]*sv[3]; \
    r2[0][5] = S27*(mx[4]*sv[6] + mx[6]*sv[4]) - S37*mx[5]*sv[5]; \
    r2[1][5] = S37*(mx[4]*sv[7] + mx[7]*sv[4]) - C114*(mx[5]*sv[6] + mx[6]*sv[5]); \
    r2[2][5] = S27*(mx[8]*sv[4] + mx[4]*sv[8] - mx[6]*sv[6]) + C114*(mx[7]*sv[5] + mx[5]*sv[7]); \
    r2[3][5] = S37*(mx[8]*sv[5] + mx[5]*sv[8]) - C114*(mx[7]*sv[6] + mx[6]*sv[7]); \
    r2[4][5] = S27*(mx[8]*sv[6] + mx[6]*sv[8]) - S37*mx[7]*sv[7];

// ---------------- kernel A: vmp + node-CG + wn mix -> mixed[256][72] -------
__global__ __launch_bounds__(256) void k_nodes(
                        const float* __restrict__ adj,
                        const float* __restrict__ v0,
                        const float* __restrict__ v1,
                        const float* __restrict__ v2,
                        const float* __restrict__ wn0,
                        const float* __restrict__ wn1,
                        const float* __restrict__ wn2,
                        float* __restrict__ mixed,
                        float* __restrict__ psum){
  __shared__ float part[4][72];
  int i = blockIdx.x;
  int tid = threadIdx.x, wv = tid >> 6, lane = tid & 63;
  if (i == 0 && tid < 3) psum[tid] = 0.f;
  {
    const float* vp1; int st1;
    if (lane < 8)       { vp1 = v0 + lane;      st1 = 8;  }
    else if (lane < 32) { vp1 = v1 + (lane-8);  st1 = 24; }
    else                { vp1 = v2 + (lane-32); st1 = 40; }
    const float* vp2 = v2 + 32 + lane;
    const float* arow = adj + i*NN;
    int j0 = wv*64;
    float a1a = 0.f, a1b = 0.f, a2a = 0.f, a2b = 0.f;
    #pragma unroll 8
    for (int j = j0; j < j0+64; j += 2){
      float av0 = arow[j], av1 = arow[j+1];
      a1a = fmaf(av0, vp1[j*st1], a1a);
      a1b = fmaf(av1, vp1[(j+1)*st1], a1b);
      if (lane < 8){
        a2a = fmaf(av0, vp2[j*40], a2a);
        a2b = fmaf(av1, vp2[(j+1)*40], a2b);
      }
    }
    part[wv][lane] = a1a + a1b;
    if (lane < 8) part[wv][64+lane] = a2a + a2b;
  }
  __syncthreads();
  if (wv) return;
  {
    float s = part[0][lane] + part[1][lane] + part[2][lane] + part[3][lane];
    float s2 = 0.f;
    if (lane < 8)
      s2 = part[0][64+lane] + part[1][64+lane] + part[2][64+lane] + part[3][64+lane];
    part[0][lane] = s;
    if (lane < 8) part[0][64+lane] = s2;
  }
  int c = lane >> 3, d = lane & 7;
  float mx[9], sv[9];
  #pragma unroll
  for (int j=0;j<9;j++){ mx[j] = part[0][j*8 + c]; sv[j] = part[0][j*8 + d]; }
  float r0[3], r1[3][6], r2[5][6];
  CGREL(mx, sv, r0, r1, r2)

  float a0[8], a1m[3][8], a2m[5][8];
  #pragma unroll
  for (int dp=0;dp<8;dp++){ a0[dp]=0.f;
    #pragma unroll
    for (int M=0;M<3;M++) a1m[M][dp]=0.f;
    #pragma unroll
    for (int M=0;M<5;M++) a2m[M][dp]=0.f;
  }
  #pragma unroll
  for (int k=0;k<3;k++){
    const float* row = wn0 + (k*64 + lane)*8;
    float4 u = *(const float4*)row;
    float4 v = *(const float4*)(row+4);
    float u8[8] = {u.x,u.y,u.z,u.w,v.x,v.y,v.z,v.w};
    #pragma unroll
    for (int dp=0;dp<8;dp++) a0[dp] = fmaf(r0[k], u8[dp], a0[dp]);
  }
  #pragma unroll
  for (int k=0;k<6;k++){
    const float* row = wn1 + (k*64 + lane)*8;
    float4 u = *(const float4*)row;
    float4 v = *(const float4*)(row+4);
    float u8[8] = {u.x,u.y,u.z,u.w,v.x,v.y,v.z,v.w};
    #pragma unroll
    for (int M=0;M<3;M++)
      #pragma unroll
      for (int dp=0;dp<8;dp++) a1m[M][dp] = fmaf(r1[M][k], u8[dp], a1m[M][dp]);
  }
  #pragma unroll
  for (int k=0;k<6;k++){
    const float* row = wn2 + (k*64 + lane)*8;
    float4 u = *(const float4*)row;
    float4 v = *(const float4*)(row+4);
    float u8[8] = {u.x,u.y,u.z,u.w,v.x,v.y,v.z,v.w};
    #pragma unroll
    for (int M=0;M<5;M++)
      #pragma unroll
      for (int dp=0;dp<8;dp++) a2m[M][dp] = fmaf(r2[M][k], u8[dp], a2m[M][dp]);
  }
  #pragma unroll
  for (int m=0;m<9;m++){
    #pragma unroll
    for (int dp=0;dp<8;dp++){
      float val = (m==0) ? a0[dp] : (m<4 ? a1m[m-1][dp] : a2m[m-4][dp]);
      val += __shfl_xor(val, 1);
      val += __shfl_xor(val, 2);
      val += __shfl_xor(val, 4);
      val += __shfl_xor(val, 8);
      val += __shfl_xor(val, 16);
      val += __shfl_xor(val, 32);
      if (lane == ((m*8+dp) & 63)) mixed[i*72 + m*8 + dp] = val;
    }
  }
}

// ---------------- kernel B: pairwise CG + wr mix, nt float4 stream ---------
// Lane = (c2, dq) = (lane>>1, lane&1). Lane owns channel c2 (+ c2+32 for
// wr1/wr2) x 4 taus (d = dq*4..dq*4+3). 5 nt float4 loads/pair (1 KB/instr).
__device__ __forceinline__ float sel3(float a0, float a1, float a2, int k){
  float r = (k==1) ? a1 : a0;
  return (k>=2) ? a2 : r;
}
__device__ __forceinline__ float sel4(float a0, float a1, float a2, float a3, int k){
  float lo = (k&1) ? a1 : a0;
  float hi = (k&1) ? a3 : a2;
  return (k&2) ? hi : lo;
}

__global__ __launch_bounds__(256) void k_pair(
    const float* __restrict__ mixed,
    const float* __restrict__ s0, const float* __restrict__ s1, const float* __restrict__ s2,
    const float* __restrict__ wr0, const float* __restrict__ wr1, const float* __restrict__ wr2,
    float* __restrict__ part, float* __restrict__ psum){
  __shared__ float red[4][72];
  __shared__ float bp[3];
  int tid = threadIdx.x;
  int wv = tid >> 6, lane = tid & 63;
  int y = blockIdx.x & (NN-1);
  int xsel = blockIdx.x >> 8;              // 0..7
  int xbase = (xsel*4 + wv) * XPW;

  int c2 = lane >> 1, dq = lane & 1;
  int tc = c2 & 7;
  int c0c = (c2 < 24) ? c2 : 23;           // wr0 clamp
  int cb  = c2 & 15;                        // b-batch channel - 32
  int k0  = c2 >> 3;                        // 0..3 (3 == invalid for wr0)
  int kb  = cb >> 3;                        // 0..1 -> chunks 4,5
  bool v0ok = (c2 < 24);
  bool vbok = (c2 < 16);

  vf4 acc[9];
  #pragma unroll
  for (int m=0;m<9;m++) acc[m] = (vf4)0.f;

  for (int i=0;i<XPW;i++){
    int x = xbase + i;
    int pxy = x*NN + y;
    const vf4* q0 = (const vf4*)(wr0 + (size_t)pxy*192);
    const vf4* q1 = (const vf4*)(wr1 + (size_t)pxy*384);
    const vf4* q2 = (const vf4*)(wr2 + (size_t)pxy*384);
    vf4 w0  = __builtin_nontemporal_load(q0 + (c0c*2 + dq));
    vf4 w1a = __builtin_nontemporal_load(q1 + (c2*2 + dq));
    vf4 w1b = __builtin_nontemporal_load(q1 + ((32+cb)*2 + dq));
    vf4 w2a = __builtin_nontemporal_load(q2 + (c2*2 + dq));
    vf4 w2b = __builtin_nontemporal_load(q2 + ((32+cb)*2 + dq));

    float mx[9], sv[9];
    {
      const float* mb = mixed + x*72 + tc;
      #pragma unroll
      for (int j=0;j<9;j++) mx[j] = mb[j*8];
      sv[0] = s0[pxy];
      #pragma unroll
      for (int j=0;j<3;j++) sv[1+j] = s1[(size_t)pxy*3+j];
      #pragma unroll
      for (int j=0;j<5;j++) sv[4+j] = s2[(size_t)pxy*5+j];
    }

    float r0[3], r1[3][6], r2[5][6];
    CGREL(mx, sv, r0, r1, r2)

    // per-lane chunk selection (cndmask chains; no runtime array indexing)
    float g0 = v0ok ? sel3(r0[0], r0[1], r0[2], k0) : 0.f;
    float g1a[3], g1b[3], g2a[5], g2b[5];
    #pragma unroll
    for (int M=0;M<3;M++){
      g1a[M] = sel4(r1[M][0], r1[M][1], r1[M][2], r1[M][3], k0);
      g1b[M] = vbok ? (kb ? r1[M][5] : r1[M][4]) : 0.f;
    }
    #pragma unroll
    for (int M=0;M<5;M++){
      g2a[M] = sel4(r2[M][0], r2[M][1], r2[M][2], r2[M][3], k0);
      g2b[M] = vbok ? (kb ? r2[M][5] : r2[M][4]) : 0.f;
    }

    acc[0] += g0 * w0;
    #pragma unroll
    for (int M=0;M<3;M++) acc[1+M] += g1a[M]*w1a + g1b[M]*w1b;
    #pragma unroll
    for (int M=0;M<5;M++) acc[4+M] += g2a[M]*w2a + g2b[M]*w2b;
  }

  // reduce across lanes with same dq (xor masks 2..32), per component
  #pragma unroll
  for (int m=0;m<9;m++){
    #pragma unroll
    for (int comp=0;comp<4;comp++){
      float v = acc[m][comp];
      v += __shfl_xor(v, 2);
      v += __shfl_xor(v, 4);
      v += __shfl_xor(v, 8);
      v += __shfl_xor(v, 16);
      v += __shfl_xor(v, 32);
      acc[m][comp] = v;
    }
  }
  if (lane < 2){
    #pragma unroll
    for (int m=0;m<9;m++)
      *(vf4*)&red[wv][m*8 + lane*4] = acc[m];   // lane == dq here
  }
  if (tid < 3) bp[tid] = 0.f;
  __syncthreads();
  if (tid < 72){
    float v = red[0][tid] + red[1][tid] + red[2][tid] + red[3][tid];
    part[((size_t)xsel*NN + y)*72 + tid] = v;
    int mall = tid >> 3;
    int l = (mall==0) ? 0 : (mall < 4 ? 1 : 2);
    atomicAdd(&bp[l], v);
  }
  __syncthreads();
  if (tid < 3) atomicAdd(&psum[tid], bp[tid]);
}

// ---------------- kernel C: gather partials + normalize + write ------------
__global__ __launch_bounds__(256) void k_final(
    const float* __restrict__ part, const float* __restrict__ psum,
    float* __restrict__ out){
  int idx = blockIdx.x*256 + threadIdx.x;   // 72 blocks -> 18432 exactly
  int y = idx / 72;
  int t = idx - y*72;
  float v = 0.f;
  #pragma unroll
  for (int x=0; x<NXS; x++) v += part[((size_t)x*NN + y)*72 + t];
  int mall = t >> 3;
  float den = (mall == 0) ? psum[0] : (mall < 4 ? psum[1] : psum[2]);
  out[idx] = v / den;
}

extern "C" void kernel_launch(void* const* d_in, const int* in_sizes, int n_in,
                              void* d_out, int out_size, void* d_ws, size_t ws_size,
                              hipStream_t stream) {
  const float* v0  = (const float*)d_in[0];
  const float* v1  = (const float*)d_in[1];
  const float* v2  = (const float*)d_in[2];
  const float* adj = (const float*)d_in[3];
  const float* s0  = (const float*)d_in[4];
  const float* s1  = (const float*)d_in[5];
  const float* s2  = (const float*)d_in[6];
  const float* wn0 = (const float*)d_in[7];
  const float* wn1 = (const float*)d_in[8];
  const float* wn2 = (const float*)d_in[9];
  const float* wr0 = (const float*)d_in[10];
  const float* wr1 = (const float*)d_in[11];
  const float* wr2 = (const float*)d_in[12];
  float* out = (float*)d_out;

  float* ws    = (float*)d_ws;
  float* mixed = ws;                       // 18432
  float* part  = ws + 18432;               // NXS*256*72 = 147456
  float* psum  = ws + 18432 + 147456;      // 3

  k_nodes<<<NN, 256, 0, stream>>>(adj, v0, v1, v2, wn0, wn1, wn2, mixed, psum);
  k_pair<<<NN*NXS, 256, 0, stream>>>(mixed, s0, s1, s2, wr0, wr1, wr2, part, psum);
  k_final<<<72, 256, 0, stream>>>(part, psum, out);
}

// Round 14
// 79.259 us; speedup vs baseline: 1.0991x; 1.0991x over previous
//
#include <hip/hip_runtime.h>

#define NN 256
#define XPW 8              // pairs (x values) per wave
#define NXS (NN/(4*XPW))   // 8 xsel groups

// hard-coded CG constants (l<=2), float32
#define C13  0.5773502691896258f
#define C15  0.4472135954999579f
#define CC12 0.7071067811865476f
#define S35  0.7745966692414834f
#define S310 0.5477225575051661f
#define C110 0.3162277660168379f
#define S25  0.6324555320336759f
#define S23  0.8164965809277260f
#define C16  0.4082482904638630f
#define S27  0.5345224838248488f
#define S37  0.6546536707079771f
#define C114 0.2672612419124244f

#define CGREL(mx, sv, r0, r1, r2) \
    r0[0] = mx[0]*sv[0]; \
    r0[1] = C13*(mx[1]*sv[3] - mx[2]*sv[2] + mx[3]*sv[1]); \
    r0[2] = C15*(mx[4]*sv[8] - mx[5]*sv[7] + mx[6]*sv[6] - mx[7]*sv[5] + mx[8]*sv[4]); \
    r1[0][0] = mx[0]*sv[1]; r1[1][0] = mx[0]*sv[2]; r1[2][0] = mx[0]*sv[3]; \
    r1[0][1] = mx[1]*sv[0]; r1[1][1] = mx[2]*sv[0]; r1[2][1] = mx[3]*sv[0]; \
    r1[0][2] = CC12*(mx[2]*sv[1] - mx[1]*sv[2]); \
    r1[1][2] = CC12*(mx[3]*sv[1] - mx[1]*sv[3]); \
    r1[2][2] = CC12*(mx[3]*sv[2] - mx[2]*sv[3]); \
    r1[0][3] = S35*mx[3]*sv[4] - S310*mx[2]*sv[5] + C110*mx[1]*sv[6]; \
    r1[1][3] = S310*(mx[3]*sv[5] + mx[1]*sv[7]) - S25*mx[2]*sv[6]; \
    r1[2][3] = S35*mx[1]*sv[8] - S310*mx[2]*sv[7] + C110*mx[3]*sv[6]; \
    r1[0][4] = C110*mx[6]*sv[1] - S310*mx[5]*sv[2] + S35*mx[4]*sv[3]; \
    r1[1][4] = S310*(mx[7]*sv[1] + mx[5]*sv[3]) - S25*mx[6]*sv[2]; \
    r1[2][4] = S35*mx[8]*sv[1] - S310*mx[7]*sv[2] + C110*mx[6]*sv[3]; \
    r1[0][5] = C15*(mx[7]*sv[4] - mx[4]*sv[7]) + S310*(mx[5]*sv[6] - mx[6]*sv[5]); \
    r1[1][5] = S25*(mx[8]*sv[4] - mx[4]*sv[8]) + C110*(mx[5]*sv[7] - mx[7]*sv[5]); \
    r1[2][5] = C15*(mx[8]*sv[5] - mx[5]*sv[8]) + S310*(mx[6]*sv[7] - mx[7]*sv[6]); \
    r2[0][0]=mx[0]*sv[4]; r2[1][0]=mx[0]*sv[5]; r2[2][0]=mx[0]*sv[6]; r2[3][0]=mx[0]*sv[7]; r2[4][0]=mx[0]*sv[8]; \
    r2[0][1] = mx[1]*sv[1]; \
    r2[1][1] = CC12*(mx[2]*sv[1] + mx[1]*sv[2]); \
    r2[2][1] = C16*(mx[3]*sv[1] + mx[1]*sv[3]) + S23*mx[2]*sv[2]; \
    r2[3][1] = CC12*(mx[3]*sv[2] + mx[2]*sv[3]); \
    r2[4][1] = mx[3]*sv[3]; \
    r2[0][2] = S23*mx[2]*sv[4] - C13*mx[1]*sv[5]; \
    r2[1][2] = C13*mx[3]*sv[4] + C16*mx[2]*sv[5] - CC12*mx[1]*sv[6]; \
    r2[2][2] = CC12*(mx[3]*sv[5] - mx[1]*sv[7]); \
    r2[3][2] = CC12*mx[3]*sv[6] - C16*mx[2]*sv[7] - C13*mx[1]*sv[8]; \
    r2[4][2] = C13*mx[3]*sv[7] - S23*mx[2]*sv[8]; \
    r2[0][3]=mx[4]*sv[0]; r2[1][3]=mx[5]*sv[0]; r2[2][3]=mx[6]*sv[0]; r2[3][3]=mx[7]*sv[0]; r2[4][3]=mx[8]*sv[0]; \
    r2[0][4] = C13*mx[5]*sv[1] - S23*mx[4]*sv[2]; \
    r2[1][4] = CC12*mx[6]*sv[1] - C16*mx[5]*sv[2] - C13*mx[4]*sv[3]; \
    r2[2][4] = CC12*(mx[7]*sv[1] - mx[5]*sv[3]); \
    r2[3][4] = C13*mx[8]*sv[1] + C16*mx[7]*sv[2] - CC12*mx[6]*sv[3]; \
    r2[4][4] = S23*mx[8]*sv[2] - C13*mx[7]*sv[3]; \
    r2[0][5] = S27*(mx[4]*sv[6] + mx[6]*sv[4]) - S37*mx[5]*sv[5]; \
    r2[1][5] = S37*(mx[4]*sv[7] + mx[7]*sv[4]) - C114*(mx[5]*sv[6] + mx[6]*sv[5]); \
    r2[2][5] = S27*(mx[8]*sv[4] + mx[4]*sv[8] - mx[6]*sv[6]) + C114*(mx[7]*sv[5] + mx[5]*sv[7]); \
    r2[3][5] = S37*(mx[8]*sv[5] + mx[5]*sv[8]) - C114*(mx[7]*sv[6] + mx[6]*sv[7]); \
    r2[4][5] = S27*(mx[8]*sv[6] + mx[6]*sv[8]) - S37*mx[7]*sv[7];

// ---------------- kernel A: vmp + node-CG + wn mix -> mixed[256][72] -------
// block 0 also zeroes psum[3] (runs strictly before k_pair in stream order).
__global__ __launch_bounds__(256) void k_nodes(
                        const float* __restrict__ adj,
                        const float* __restrict__ v0,
                        const float* __restrict__ v1,
                        const float* __restrict__ v2,
                        const float* __restrict__ wn0,
                        const float* __restrict__ wn1,
                        const float* __restrict__ wn2,
                        float* __restrict__ mixed,
                        float* __restrict__ psum){
  __shared__ float part[4][72];
  int i = blockIdx.x;
  int tid = threadIdx.x, wv = tid >> 6, lane = tid & 63;
  if (i == 0 && tid < 3) psum[tid] = 0.f;
  {
    const float* vp1; int st1;
    if (lane < 8)       { vp1 = v0 + lane;      st1 = 8;  }
    else if (lane < 32) { vp1 = v1 + (lane-8);  st1 = 24; }
    else                { vp1 = v2 + (lane-32); st1 = 40; }
    const float* vp2 = v2 + 32 + lane;
    const float* arow = adj + i*NN;
    int j0 = wv*64;
    float a1a = 0.f, a1b = 0.f, a2a = 0.f, a2b = 0.f;
    #pragma unroll 8
    for (int j = j0; j < j0+64; j += 2){
      float av0 = arow[j], av1 = arow[j+1];
      a1a = fmaf(av0, vp1[j*st1], a1a);
      a1b = fmaf(av1, vp1[(j+1)*st1], a1b);
      if (lane < 8){
        a2a = fmaf(av0, vp2[j*40], a2a);
        a2b = fmaf(av1, vp2[(j+1)*40], a2b);
      }
    }
    part[wv][lane] = a1a + a1b;
    if (lane < 8) part[wv][64+lane] = a2a + a2b;
  }
  __syncthreads();
  if (wv) return;
  {
    float s = part[0][lane] + part[1][lane] + part[2][lane] + part[3][lane];
    float s2 = 0.f;
    if (lane < 8)
      s2 = part[0][64+lane] + part[1][64+lane] + part[2][64+lane] + part[3][64+lane];
    part[0][lane] = s;
    if (lane < 8) part[0][64+lane] = s2;
  }
  int c = lane >> 3, d = lane & 7;
  float mx[9], sv[9];
  #pragma unroll
  for (int j=0;j<9;j++){ mx[j] = part[0][j*8 + c]; sv[j] = part[0][j*8 + d]; }
  float r0[3], r1[3][6], r2[5][6];
  CGREL(mx, sv, r0, r1, r2)

  float a0[8], a1m[3][8], a2m[5][8];
  #pragma unroll
  for (int dp=0;dp<8;dp++){ a0[dp]=0.f;
    #pragma unroll
    for (int M=0;M<3;M++) a1m[M][dp]=0.f;
    #pragma unroll
    for (int M=0;M<5;M++) a2m[M][dp]=0.f;
  }
  #pragma unroll
  for (int k=0;k<3;k++){
    const float* row = wn0 + (k*64 + lane)*8;
    float4 u = *(const float4*)row;
    float4 v = *(const float4*)(row+4);
    float u8[8] = {u.x,u.y,u.z,u.w,v.x,v.y,v.z,v.w};
    #pragma unroll
    for (int dp=0;dp<8;dp++) a0[dp] = fmaf(r0[k], u8[dp], a0[dp]);
  }
  #pragma unroll
  for (int k=0;k<6;k++){
    const float* row = wn1 + (k*64 + lane)*8;
    float4 u = *(const float4*)row;
    float4 v = *(const float4*)(row+4);
    float u8[8] = {u.x,u.y,u.z,u.w,v.x,v.y,v.z,v.w};
    #pragma unroll
    for (int M=0;M<3;M++)
      #pragma unroll
      for (int dp=0;dp<8;dp++) a1m[M][dp] = fmaf(r1[M][k], u8[dp], a1m[M][dp]);
  }
  #pragma unroll
  for (int k=0;k<6;k++){
    const float* row = wn2 + (k*64 + lane)*8;
    float4 u = *(const float4*)row;
    float4 v = *(const float4*)(row+4);
    float u8[8] = {u.x,u.y,u.z,u.w,v.x,v.y,v.z,v.w};
    #pragma unroll
    for (int M=0;M<5;M++)
      #pragma unroll
      for (int dp=0;dp<8;dp++) a2m[M][dp] = fmaf(r2[M][k], u8[dp], a2m[M][dp]);
  }
  #pragma unroll
  for (int m=0;m<9;m++){
    #pragma unroll
    for (int dp=0;dp<8;dp++){
      float val = (m==0) ? a0[dp] : (m<4 ? a1m[m-1][dp] : a2m[m-4][dp]);
      val += __shfl_xor(val, 1);
      val += __shfl_xor(val, 2);
      val += __shfl_xor(val, 4);
      val += __shfl_xor(val, 8);
      val += __shfl_xor(val, 16);
      val += __shfl_xor(val, 32);
      if (lane == ((m*8+dp) & 63)) mixed[i*72 + m*8 + dp] = val;
    }
  }
}

// ---------------- kernel B: pairwise CG + wr mix -> per-block partials -----
// 2048 blocks x 4 waves. nt wr loads. No atomics into vsum: block (y,xsel)
// overwrites part[(xsel*NN+y)*72 + t]. Part sums via 3 atomics/block.
__global__ __launch_bounds__(256) void k_pair(
    const float* __restrict__ mixed,
    const float* __restrict__ s0, const float* __restrict__ s1, const float* __restrict__ s2,
    const float* __restrict__ wr0, const float* __restrict__ wr1, const float* __restrict__ wr2,
    float* __restrict__ part, float* __restrict__ psum){
  __shared__ float red[4][72];
  __shared__ float bp[3];
  int tid = threadIdx.x;
  int wv = tid >> 6, lane = tid & 63;
  int y = blockIdx.x & (NN-1);
  int xsel = blockIdx.x >> 8;              // 0..7
  int xbase = (xsel*4 + wv) * XPW;
  int cgp = lane >> 3;

  float acc[9];
  #pragma unroll
  for (int m=0;m<9;m++) acc[m]=0.f;

  for (int i=0;i<XPW;i++){
    int x = xbase + i;
    int pxy = x*NN + y;
    const float* p0 = wr0 + (size_t)pxy*192 + lane;
    const float* p1 = wr1 + (size_t)pxy*384 + lane;
    const float* p2 = wr2 + (size_t)pxy*384 + lane;
    float w0v[3], w1v[6], w2v[6];
    #pragma unroll
    for (int k=0;k<3;k++) w0v[k] = __builtin_nontemporal_load(p0 + k*64);
    #pragma unroll
    for (int k=0;k<6;k++) w1v[k] = __builtin_nontemporal_load(p1 + k*64);
    #pragma unroll
    for (int k=0;k<6;k++) w2v[k] = __builtin_nontemporal_load(p2 + k*64);

    float mx[9], sv[9];
    {
      const float* mb = mixed + x*72 + cgp;
      #pragma unroll
      for (int j=0;j<9;j++) mx[j] = mb[j*8];
      sv[0] = s0[pxy];
      #pragma unroll
      for (int j=0;j<3;j++) sv[1+j] = s1[(size_t)pxy*3+j];
      #pragma unroll
      for (int j=0;j<5;j++) sv[4+j] = s2[(size_t)pxy*5+j];
    }

    float r0[3], r1[3][6], r2[5][6];
    CGREL(mx, sv, r0, r1, r2)

    #pragma unroll
    for (int k=0;k<3;k++) acc[0] = fmaf(r0[k], w0v[k], acc[0]);
    #pragma unroll
    for (int k=0;k<6;k++){
      acc[1] = fmaf(r1[0][k], w1v[k], acc[1]);
      acc[2] = fmaf(r1[1][k], w1v[k], acc[2]);
      acc[3] = fmaf(r1[2][k], w1v[k], acc[3]);
      acc[4] = fmaf(r2[0][k], w2v[k], acc[4]);
      acc[5] = fmaf(r2[1][k], w2v[k], acc[5]);
      acc[6] = fmaf(r2[2][k], w2v[k], acc[6]);
      acc[7] = fmaf(r2[3][k], w2v[k], acc[7]);
      acc[8] = fmaf(r2[4][k], w2v[k], acc[8]);
    }
  }

  // reduce over cgp groups (lane bits 3..5)
  #pragma unroll
  for (int m=0;m<9;m++){
    float v = acc[m];
    v += __shfl_xor(v, 8);
    v += __shfl_xor(v, 16);
    v += __shfl_xor(v, 32);
    acc[m] = v;
  }
  if (lane < 8){
    #pragma unroll
    for (int m=0;m<9;m++) red[wv][m*8+lane] = acc[m];
  }
  if (tid < 3) bp[tid] = 0.f;
  __syncthreads();
  if (tid < 72){
    float v = red[0][tid] + red[1][tid] + red[2][tid] + red[3][tid];
    part[((size_t)xsel*NN + y)*72 + tid] = v;
    int mall = tid >> 3;
    int l = (mall==0) ? 0 : (mall < 4 ? 1 : 2);
    atomicAdd(&bp[l], v);
  }
  __syncthreads();
  if (tid < 3) atomicAdd(&psum[tid], bp[tid]);
}

// ---------------- kernel C: gather partials + normalize + write ------------
__global__ __launch_bounds__(256) void k_final(
    const float* __restrict__ part, const float* __restrict__ psum,
    float* __restrict__ out){
  int idx = blockIdx.x*256 + threadIdx.x;   // 72 blocks -> 18432 exactly
  int y = idx / 72;
  int t = idx - y*72;
  float v = 0.f;
  #pragma unroll
  for (int x=0; x<NXS; x++) v += part[((size_t)x*NN + y)*72 + t];
  int mall = t >> 3;
  float den = (mall == 0) ? psum[0] : (mall < 4 ? psum[1] : psum[2]);
  out[idx] = v / den;
}

extern "C" void kernel_launch(void* const* d_in, const int* in_sizes, int n_in,
                              void* d_out, int out_size, void* d_ws, size_t ws_size,
                              hipStream_t stream) {
  const float* v0  = (const float*)d_in[0];
  const float* v1  = (const float*)d_in[1];
  const float* v2  = (const float*)d_in[2];
  const float* adj = (const float*)d_in[3];
  const float* s0  = (const float*)d_in[4];
  const float* s1  = (const float*)d_in[5];
  const float* s2  = (const float*)d_in[6];
  const float* wn0 = (const float*)d_in[7];
  const float* wn1 = (const float*)d_in[8];
  const float* wn2 = (const float*)d_in[9];
  const float* wr0 = (const float*)d_in[10];
  const float* wr1 = (const float*)d_in[11];
  const float* wr2 = (const float*)d_in[12];
  float* out = (float*)d_out;

  float* ws    = (float*)d_ws;
  float* mixed = ws;                       // 18432
  float* part  = ws + 18432;               // NXS*256*72 = 147456
  float* psum  = ws + 18432 + 147456;      // 3

  k_nodes<<<NN, 256, 0, stream>>>(adj, v0, v1, v2, wn0, wn1, wn2, mixed, psum);
  k_pair<<<NN*NXS, 256, 0, stream>>>(mixed, s0, s1, s2, wr0, wr1, wr2, part, psum);
  k_final<<<72, 256, 0, stream>>>(part, psum, out);
}